// Round 3
// 868.356 us; speedup vs baseline: 1.0743x; 1.0743x over previous
//
#include <hip/hip_runtime.h>
#include <math.h>

#define GRID 2048
#define BLOCK 256
#define SGRID 128                       // sample-kernel blocks
#define SAMPLE_F4 (2LL * 1024 * 1024)   // 2M float4 = 8M floats = 32 MiB sample

typedef float nfloat4 __attribute__((ext_vector_type(4)));  // native vec for nt-store

// Block-wide max reduction (wave-64 shfl + LDS). Leading __syncthreads()
// protects smem reuse across repeated calls within one kernel.
__device__ __forceinline__ float block_reduce_max(float m) {
    #pragma unroll
    for (int off = 32; off > 0; off >>= 1)
        m = fmaxf(m, __shfl_down(m, off, 64));
    __shared__ float smem[BLOCK / 64];
    __syncthreads();
    if ((threadIdx.x & 63) == 0) smem[threadIdx.x >> 6] = m;
    __syncthreads();
    return fmaxf(fmaxf(smem[0], smem[1]), fmaxf(smem[2], smem[3]));
}

// Exponent + scales exactly as the reference: me = clip(floor(log2(max(|x|,1e-10))), -128, 127)
__device__ __forceinline__ void bq_scales(float bm, int* me_out, float* s, float* inv) {
    bm = fmaxf(bm, 1e-10f);                    // magnitude floor
    int me = ilogbf(bm);                       // floor(log2(bm)) exactly
    me = me < -128 ? -128 : (me > 127 ? 127 : me);
    *me_out = me;
    *s   = ldexpf(1.0f, 6 - me);               // s   = 2^(-me + (bits-2))
    *inv = ldexpf(1.0f, me - 6);               // inv = 2^(me - (bits-2))
}

__device__ __forceinline__ float bq_one(float x, float s, float inv) {
    // data = where(x >= 0, max(x, 1e-10), min(x, -1e-10));  -0.0 >= 0 is true
    float d = (x >= 0.0f) ? fmaxf(x, 1e-10f) : fminf(x, -1e-10f);
    float i = rintf(d * s);                    // half-to-even == jnp.round
    i = fminf(fmaxf(i, -128.0f), 127.0f);      // clip to [-2^7, 2^7-1]
    return i * inv;
}

// k1: sample max over the first min(n4, 2M) float4s -> speculative exponent source.
// Each block writes its own spart slot (poison-safe).
__global__ __launch_bounds__(BLOCK) void bq_smax_kernel(
    const float4* __restrict__ x, float* __restrict__ spart, long long n4) {
    long long limit = n4 < SAMPLE_F4 ? n4 : SAMPLE_F4;
    float m = 0.0f;
    long long stride = (long long)gridDim.x * blockDim.x;
    for (long long i = (long long)blockIdx.x * blockDim.x + threadIdx.x;
         i < limit; i += stride) {
        float4 v = x[i];
        m = fmaxf(m, fmaxf(fmaxf(fabsf(v.x), fabsf(v.y)),
                           fmaxf(fabsf(v.z), fabsf(v.w))));
    }
    float bm = block_reduce_max(m);
    if (threadIdx.x == 0) spart[blockIdx.x] = bm;
}

// k2: ONE sweep over x — true per-block max (for verification) + quantize with
// the speculative scale + non-temporal store. Forward order: k1's 32 MiB is L3-hot.
__global__ __launch_bounds__(BLOCK) void bq_specquant_kernel(
    const float4* __restrict__ x, nfloat4* __restrict__ out,
    float* __restrict__ partials, const float* __restrict__ spart,
    long long n4, const float* __restrict__ x_scalar,
    float* __restrict__ out_scalar, long long n) {
    // uniform speculative exponent from the 128 sample partials (L2-hot, tiny)
    float sm0 = spart[threadIdx.x & (SGRID - 1)];
    float smax = block_reduce_max(sm0);
    int me_spec; float s, inv;
    bq_scales(smax, &me_spec, &s, &inv);

    float m = 0.0f;
    long long stride = (long long)gridDim.x * blockDim.x;
    for (long long i = (long long)blockIdx.x * blockDim.x + threadIdx.x;
         i < n4; i += stride) {
        float4 v = x[i];
        m = fmaxf(m, fmaxf(fmaxf(fabsf(v.x), fabsf(v.y)),
                           fmaxf(fabsf(v.z), fabsf(v.w))));
        nfloat4 r;
        r.x = bq_one(v.x, s, inv);
        r.y = bq_one(v.y, s, inv);
        r.z = bq_one(v.z, s, inv);
        r.w = bq_one(v.w, s, inv);
        __builtin_nontemporal_store(r, &out[i]);
    }
    // scalar tail: fold into the true max AND quantize speculatively
    if (blockIdx.x == 0 && threadIdx.x == 0) {
        for (long long i = n4 * 4; i < n; ++i) {
            float xv = x_scalar[i];
            m = fmaxf(m, fabsf(xv));
            out_scalar[i] = bq_one(xv, s, inv);
        }
    }
    float bm = block_reduce_max(m);
    if (threadIdx.x == 0) partials[blockIdx.x] = bm;   // own slot, plain store
}

// k3: verify. Exact global exponent from the true partials; if it matches the
// speculative one (recomputed identically), all blocks exit. Else requantize all.
__global__ __launch_bounds__(BLOCK) void bq_fixup_kernel(
    const float4* __restrict__ x, nfloat4* __restrict__ out,
    const float* __restrict__ partials, const float* __restrict__ spart,
    long long n4, const float* __restrict__ x_scalar,
    float* __restrict__ out_scalar, long long n) {
    float m = 0.0f;
    #pragma unroll
    for (int k = 0; k < GRID / BLOCK; ++k)
        m = fmaxf(m, partials[threadIdx.x + k * BLOCK]);
    float gm = block_reduce_max(m);
    int me_g; float s, inv;
    bq_scales(gm, &me_g, &s, &inv);

    float sm0 = spart[threadIdx.x & (SGRID - 1)];
    float smax = block_reduce_max(sm0);
    int me_spec; float s_u, inv_u;
    bq_scales(smax, &me_spec, &s_u, &inv_u);

    if (me_g == me_spec) return;   // speculation held: output already exact

    // slow path (distribution-independent correctness): full requantize
    long long stride = (long long)gridDim.x * blockDim.x;
    for (long long i = (long long)blockIdx.x * blockDim.x + threadIdx.x;
         i < n4; i += stride) {
        float4 v = x[i];
        nfloat4 r;
        r.x = bq_one(v.x, s, inv);
        r.y = bq_one(v.y, s, inv);
        r.z = bq_one(v.z, s, inv);
        r.w = bq_one(v.w, s, inv);
        __builtin_nontemporal_store(r, &out[i]);
    }
    if (blockIdx.x == 0 && threadIdx.x == 0) {
        for (long long i = n4 * 4; i < n; ++i)
            out_scalar[i] = bq_one(x_scalar[i], s, inv);
    }
}

extern "C" void kernel_launch(void* const* d_in, const int* in_sizes, int n_in,
                              void* d_out, int out_size, void* d_ws, size_t ws_size,
                              hipStream_t stream) {
    const float* x = (const float*)d_in[0];
    float* out = (float*)d_out;
    long long n = (long long)in_sizes[0];
    long long n4 = n / 4;
    float* partials = (float*)d_ws;        // [0, GRID): true per-block maxes
    float* spart = partials + GRID;        // [GRID, GRID+SGRID): sample maxes

    bq_smax_kernel<<<SGRID, BLOCK, 0, stream>>>((const float4*)x, spart, n4);
    bq_specquant_kernel<<<GRID, BLOCK, 0, stream>>>(
        (const float4*)x, (nfloat4*)out, partials, spart, n4, x, out, n);
    bq_fixup_kernel<<<GRID, BLOCK, 0, stream>>>(
        (const float4*)x, (nfloat4*)out, partials, spart, n4, x, out, n);
}